// Round 14
// baseline (426.515 us; speedup 1.0000x reference)
//
#include <hip/hip_runtime.h>
#include <hip/hip_bf16.h>
#include <hip/hip_fp16.h>

#define HD 64
#define NODE_DIM 5
#define NEG_SLOPE 0.2f
#define SCAN_B 1024
#define NPART 8     // 8 edge slices; blockIdx%8 -> XCD round-robin heuristic
#define GT 64       // gemm node-tile per block
#define EPT 4       // edges per thread in hist/fill (independent atomic chains)

// Block = 64-node tile. W (64x64) and h-tile (64x65 padded) staged in LDS.
// Thread = (node-group, dim-quad): computes 4 nodes x 4 dims. k-loop unroll
// bounded to 8 (full unroll spilled at VGPR=256 in round 5).
// EMBED: h0 = x@embW+embB built directly in LDS. hout stored fp16 (halves the
// gather's random-read traffic); alphas computed from the fp32 accumulator
// BEFORE rounding so attention logits are exact.
template <bool EMBED>
__global__ __launch_bounds__(256) void gemm_alpha_k(
    const float* __restrict__ hin, const float* __restrict__ embW,
    const float* __restrict__ embB, const float* __restrict__ W,
    const float* __restrict__ asrc, const float* __restrict__ adst,
    __half* __restrict__ hout, float* __restrict__ alpha_s,
    float* __restrict__ alpha_d, int N) {
    __shared__ float hs[GT][HD + 1];   // 64 x 65 (pad breaks bank aliasing)
    __shared__ float Ws[HD * HD];      // 64 x 64
    __shared__ float xe[GT * NODE_DIM];      // EMBED: x tile (320)
    __shared__ float we[NODE_DIM * HD + HD]; // EMBED: embW + embB (384)
    const int t = threadIdx.x;
    const int n0 = blockIdx.x * GT;
    if (n0 >= N) return;
    const int rem = N - n0;

    // stage W: 4096 floats = 1024 float4, coalesced
    {
        const float4* w4 = (const float4*)W;
        float4* s4 = (float4*)Ws;
#pragma unroll
        for (int j = 0; j < 4; j++) s4[t + 256 * j] = w4[t + 256 * j];
    }
    if (EMBED) {
        // stage x tile (64x5=320), embW (5x64) + embB (64) = 384 — strided
        for (int j = t; j < GT * NODE_DIM; j += 256)
            xe[j] = (j < rem * NODE_DIM) ? hin[(size_t)n0 * NODE_DIM + j] : 0.0f;
        for (int j = t; j < NODE_DIM * HD + HD; j += 256)
            we[j] = (j < NODE_DIM * HD) ? embW[j] : embB[j - NODE_DIM * HD];
        __syncthreads();
        // build h0 tile: 4 threads per row, 16 dims each
        int r = t >> 2, d0 = (t & 3) * 16;
#pragma unroll
        for (int jj = 0; jj < 16; jj++) {
            int d = d0 + jj;
            float acc = we[NODE_DIM * HD + d];
#pragma unroll
            for (int k = 0; k < NODE_DIM; k++)
                acc = fmaf(xe[r * NODE_DIM + k], we[k * HD + d], acc);
            hs[r][d] = (r < rem) ? acc : 0.0f;
        }
    } else {
        // stage h tile: coalesced float4 read, padded scalar write
        const float4* g4 = (const float4*)(hin + (size_t)n0 * HD);
#pragma unroll
        for (int j = 0; j < 4; j++) {
            int idx = t + 256 * j;
            int row = idx >> 4, c4 = idx & 15;
            float4 v = {0, 0, 0, 0};
            if (row < rem) v = g4[idx];
            hs[row][c4 * 4 + 0] = v.x;
            hs[row][c4 * 4 + 1] = v.y;
            hs[row][c4 * 4 + 2] = v.z;
            hs[row][c4 * 4 + 3] = v.w;
        }
    }
    __syncthreads();

    const int dq = t & 15;    // dim quad (dims 4*dq..4*dq+3)
    const int grp = t >> 4;   // node group (nodes 4*grp..4*grp+3)
    float4 acc[4];
#pragma unroll
    for (int i = 0; i < 4; i++) acc[i] = {0, 0, 0, 0};

#pragma unroll 8
    for (int k = 0; k < 64; k++) {
        float4 w4 = *(const float4*)(Ws + k * HD + dq * 4);
#pragma unroll
        for (int i = 0; i < 4; i++) {
            float hv = hs[grp * 4 + i][k];
            acc[i].x = fmaf(hv, w4.x, acc[i].x);
            acc[i].y = fmaf(hv, w4.y, acc[i].y);
            acc[i].z = fmaf(hv, w4.z, acc[i].z);
            acc[i].w = fmaf(hv, w4.w, acc[i].w);
        }
    }

    // epilogue: store hout (fp16, 8B) + 16-lane reduce for alpha_s/alpha_d
    float4 a4 = ((const float4*)asrc)[dq];
    float4 b4 = ((const float4*)adst)[dq];
#pragma unroll
    for (int i = 0; i < 4; i++) {
        int n = n0 + grp * 4 + i;
        if (n >= N) break;
        short4 s;
        s.x = __half_as_short(__float2half_rn(acc[i].x));
        s.y = __half_as_short(__float2half_rn(acc[i].y));
        s.z = __half_as_short(__float2half_rn(acc[i].z));
        s.w = __half_as_short(__float2half_rn(acc[i].w));
        ((short4*)hout)[(size_t)n * 16 + dq] = s;
        float ps = acc[i].x * a4.x + acc[i].y * a4.y + acc[i].z * a4.z + acc[i].w * a4.w;
        float pd = acc[i].x * b4.x + acc[i].y * b4.y + acc[i].z * b4.z + acc[i].w * b4.w;
#pragma unroll
        for (int off = 8; off; off >>= 1) {   // reduce across the 16-lane group
            ps += __shfl_xor(ps, off);
            pd += __shfl_xor(pd, off);
        }
        if (dq == 0) {
            alpha_s[n] = ps;
            alpha_d[n] = pd;
        }
    }
}

// ------------- edge-sliced CSR build + merge (no self-loops in CSR) --------
// Slice p covers edges [p*Es, min((p+1)*Es, E)). merge_k concatenates each
// node's 8 slice-segments into ONE contiguous CSR (round 11: 8-segment gather
// walk cost +37%). fill/hist are latency-bound on the dependent
// load->atomic->store chain (round 13: VALU 0.7%, HBM 12%) -> EPT=4
// independent chains per thread to overlap the L3 atomic round trips.

__global__ void zero_deg_k(int* __restrict__ deg, int total) {
    int i = blockIdx.x * blockDim.x + threadIdx.x;
    if (i < total) deg[i] = 0;
}

__global__ void hist_k(const int* __restrict__ ei, int* __restrict__ deg,
                       int E, int Es, int N) {
    int part = blockIdx.x & (NPART - 1);
    int jb = (blockIdx.x >> 3) * (blockDim.x * EPT) + threadIdx.x;
    int dst[EPT];
    bool ok[EPT];
#pragma unroll
    for (int u = 0; u < EPT; u++) {
        int j = jb + u * 256;
        int g = part * Es + j;
        ok[u] = (j < Es) && (g < E);
        if (ok[u]) dst[u] = __builtin_nontemporal_load(&ei[E + g]);
    }
#pragma unroll
    for (int u = 0; u < EPT; u++)
        if (ok[u]) atomicAdd(&deg[part * N + dst[u]], 1);  // no return -> fire&forget
}

// scan of deg[p][*] per partition; blockIdx.y = partition
__global__ void scan1_k(const int* __restrict__ deg, int* __restrict__ off,
                        int* __restrict__ blksum, int N, int nb) {
    __shared__ int s[SCAN_B];
    int p = blockIdx.y;
    int gid = blockIdx.x * SCAN_B + threadIdx.x;
    int v = (gid < N) ? deg[p * N + gid] : 0;
    s[threadIdx.x] = v;
    __syncthreads();
#pragma unroll
    for (int o = 1; o < SCAN_B; o <<= 1) {
        int t = (threadIdx.x >= o) ? s[threadIdx.x - o] : 0;
        __syncthreads();
        s[threadIdx.x] += t;
        __syncthreads();
    }
    if (gid < N) off[p * (N + 1) + gid + 1] = s[threadIdx.x];
    if (threadIdx.x == SCAN_B - 1) blksum[p * nb + blockIdx.x] = s[SCAN_B - 1];
}

// blockIdx.x = partition; scans its nb block sums (nb <= 1024)
__global__ void scan2_k(int* __restrict__ blksum, int nb) {
    __shared__ int s[SCAN_B];
    int p = blockIdx.x;
    int v = ((int)threadIdx.x < nb) ? blksum[p * nb + threadIdx.x] : 0;
    s[threadIdx.x] = v;
    __syncthreads();
#pragma unroll
    for (int o = 1; o < SCAN_B; o <<= 1) {
        int t = (threadIdx.x >= o) ? s[threadIdx.x - o] : 0;
        __syncthreads();
        s[threadIdx.x] += t;
        __syncthreads();
    }
    if ((int)threadIdx.x < nb) blksum[p * nb + threadIdx.x] = s[threadIdx.x] - v;  // exclusive
}

__global__ void scan3_k(int* __restrict__ off, const int* __restrict__ deg,
                        const int* __restrict__ blksum, int* __restrict__ cursor,
                        int N, int nb) {
    int p = blockIdx.y;
    int gid = blockIdx.x * blockDim.x + threadIdx.x;
    if (gid >= N) return;
    int inc = off[p * (N + 1) + gid + 1] + blksum[p * nb + (gid >> 10)];
    off[p * (N + 1) + gid + 1] = inc;
    cursor[p * N + gid] = inc - deg[p * N + gid];
    if (gid == 0) off[p * (N + 1)] = 0;
}

__global__ void fill_csr_k(const int* __restrict__ ei, int* __restrict__ cursor,
                           int* __restrict__ csr_src, int E, int Es, int N) {
    int part = blockIdx.x & (NPART - 1);
    int jb = (blockIdx.x >> 3) * (blockDim.x * EPT) + threadIdx.x;
    int dst[EPT], src[EPT], pos[EPT];
    bool ok[EPT];
#pragma unroll
    for (int u = 0; u < EPT; u++) {
        int j = jb + u * 256;
        int g = part * Es + j;
        ok[u] = (j < Es) && (g < E);
        if (ok[u]) {
            dst[u] = __builtin_nontemporal_load(&ei[E + g]);
            src[u] = __builtin_nontemporal_load(&ei[g]);
        }
    }
#pragma unroll
    for (int u = 0; u < EPT; u++)
        if (ok[u]) pos[u] = atomicAdd(&cursor[part * N + dst[u]], 1);  // 4 chains in flight
#pragma unroll
    for (int u = 0; u < EPT; u++)
        if (ok[u]) csr_src[(size_t)part * Es + pos[u]] = src[u];
}

// thread per node: concatenate 8 slice-segments into merged CSR; emit off_tot.
__global__ void merge_k(const int* __restrict__ off_sl, const int* __restrict__ csr_sl,
                        int* __restrict__ csr_final, int* __restrict__ off_tot,
                        int N, int Es) {
    int n = blockIdx.x * blockDim.x + threadIdx.x;
    if (n >= N) return;
    int a[NPART], b[NPART];
    int base = 0;
#pragma unroll
    for (int p = 0; p < NPART; p++) {
        a[p] = off_sl[p * (N + 1) + n];
        b[p] = off_sl[p * (N + 1) + n + 1];
        base += a[p];
    }
    int w = base;
#pragma unroll
    for (int p = 0; p < NPART; p++) {
        const int* csp = csr_sl + (size_t)p * Es;
        for (int i = a[p]; i < b[p]; i++) csr_final[w++] = csp[i];
    }
    if (n == 0) off_tot[0] = 0;
    off_tot[n + 1] = w;   // == off_tot[n] + deg_tot[n]
}

// ---------------- fused attention + weighted gather ----------------
// wave = 4 nodes; 16 lanes/node; lane holds 4 dims (fp16, 8B load).
// Single contiguous CSR segment; self-loop inline. w = exp(leaky(...)) inline
// (softmax shift-invariance; logits O(±6), fp32-safe). Accumulation in fp32.
template <bool BR>
__global__ __launch_bounds__(256) void gather_k(
    const int* __restrict__ off, const int* __restrict__ csr_src,
    const float* __restrict__ as, const float* __restrict__ ad,
    const __half* __restrict__ h, const float* __restrict__ bias,
    float* __restrict__ out, int N) {
    int tid = blockIdx.x * blockDim.x + threadIdx.x;
    int wv = tid >> 6;
    int lane = threadIdx.x & 63;
    int grp = lane >> 4;
    int l16 = lane & 15;
    int n = wv * 4 + grp;
    if (n >= N) return;
    int s0 = off[n], s1 = off[n + 1];
    float adv = ad[n];
    const short4* h4 = (const short4*)h;

    // self-loop: src = n
    float e = as[n] + adv;
    e = (e >= 0.0f) ? e : NEG_SLOPE * e;
    float wsl = __expf(e);
    float l0 = wsl, l1 = 0.0f;
    short4 hvs = h4[(size_t)n * 16 + l16];
    float4 acc0, acc1 = {0, 0, 0, 0};
    acc0.x = wsl * __half2float(__short_as_half(hvs.x));
    acc0.y = wsl * __half2float(__short_as_half(hvs.y));
    acc0.z = wsl * __half2float(__short_as_half(hvs.z));
    acc0.w = wsl * __half2float(__short_as_half(hvs.w));

    int i = s0;
    for (; i + 2 <= s1; i += 2) {
        int src0 = csr_src[i], src1 = csr_src[i + 1];
        float e0 = as[src0] + adv;
        float e1 = as[src1] + adv;
        short4 hv0 = h4[(size_t)src0 * 16 + l16];
        short4 hv1 = h4[(size_t)src1 * 16 + l16];
        e0 = (e0 >= 0.0f) ? e0 : NEG_SLOPE * e0;
        e1 = (e1 >= 0.0f) ? e1 : NEG_SLOPE * e1;
        float w0 = __expf(e0), w1 = __expf(e1);
        l0 += w0; l1 += w1;
        acc0.x = fmaf(w0, __half2float(__short_as_half(hv0.x)), acc0.x);
        acc0.y = fmaf(w0, __half2float(__short_as_half(hv0.y)), acc0.y);
        acc0.z = fmaf(w0, __half2float(__short_as_half(hv0.z)), acc0.z);
        acc0.w = fmaf(w0, __half2float(__short_as_half(hv0.w)), acc0.w);
        acc1.x = fmaf(w1, __half2float(__short_as_half(hv1.x)), acc1.x);
        acc1.y = fmaf(w1, __half2float(__short_as_half(hv1.y)), acc1.y);
        acc1.z = fmaf(w1, __half2float(__short_as_half(hv1.z)), acc1.z);
        acc1.w = fmaf(w1, __half2float(__short_as_half(hv1.w)), acc1.w);
    }
    if (i < s1) {
        int src0 = csr_src[i];
        float e0 = as[src0] + adv;
        short4 hv0 = h4[(size_t)src0 * 16 + l16];
        e0 = (e0 >= 0.0f) ? e0 : NEG_SLOPE * e0;
        float w0 = __expf(e0);
        l0 += w0;
        acc0.x = fmaf(w0, __half2float(__short_as_half(hv0.x)), acc0.x);
        acc0.y = fmaf(w0, __half2float(__short_as_half(hv0.y)), acc0.y);
        acc0.z = fmaf(w0, __half2float(__short_as_half(hv0.z)), acc0.z);
        acc0.w = fmaf(w0, __half2float(__short_as_half(hv0.w)), acc0.w);
    }
    float inv = 1.0f / (l0 + l1 + 1e-16f);
    float4 r;
    r.x = (acc0.x + acc1.x) * inv;
    r.y = (acc0.y + acc1.y) * inv;
    r.z = (acc0.z + acc1.z) * inv;
    r.w = (acc0.w + acc1.w) * inv;
    if (BR) {
        float4 b = ((const float4*)bias)[l16];
        r.x = fmaxf(r.x + b.x, 0.0f);
        r.y = fmaxf(r.y + b.y, 0.0f);
        r.z = fmaxf(r.z + b.z, 0.0f);
        r.w = fmaxf(r.w + b.w, 0.0f);
    }
    ((float4*)out)[(size_t)n * 16 + l16] = r;
}

// one wave per graph: pooling + 3-layer MLP
__global__ void pool_mlp_k(const float* __restrict__ hfin, const float* __restrict__ hb,
                           const int* __restrict__ batch, int N,
                           const float* __restrict__ fc1W, const float* __restrict__ fc1b,
                           const float* __restrict__ fc2W, const float* __restrict__ fc2b,
                           const float* __restrict__ fc3W, const float* __restrict__ fc3b,
                           float* __restrict__ out) {
    __shared__ float lds[192];
    int g = blockIdx.x;
    int lane = threadIdx.x;
    int lo = 0, hi = N;
    while (lo < hi) { int mid = (lo + hi) >> 1; if (batch[mid] < g) lo = mid + 1; else hi = mid; }
    int start = lo;
    lo = start; hi = N;
    while (lo < hi) { int mid = (lo + hi) >> 1; if (batch[mid] < g + 1) lo = mid + 1; else hi = mid; }
    int end = lo;
    float bias = hb[lane];
    float sum = 0.0f, mx = -INFINITY;
    for (int n = start; n < end; n++) {
        float v = hfin[(size_t)n * HD + lane] + bias;
        sum += v;
        mx = fmaxf(mx, v);
    }
    int cnt = end - start;
    float mean = (cnt > 0) ? sum / (float)cnt : 0.0f;
    if (cnt == 0) mx = 0.0f;
    lds[lane] = mean;
    lds[64 + lane] = mx;
    __syncthreads();
    float o1 = fc1b[lane];
    for (int k = 0; k < 128; k++) o1 += lds[k] * fc1W[k * 64 + lane];
    o1 = fmaxf(o1, 0.0f);
    __syncthreads();
    lds[lane] = o1;
    __syncthreads();
    if (lane < 32) {
        float o2 = fc2b[lane];
        for (int k = 0; k < 64; k++) o2 += lds[k] * fc2W[k * 32 + lane];
        lds[128 + lane] = fmaxf(o2, 0.0f);
    }
    __syncthreads();
    if (lane == 0) {
        float o3 = fc3b[0];
        for (int k = 0; k < 32; k++) o3 += lds[128 + k] * fc3W[k];
        out[g] = o3;
    }
}

static inline size_t align256(size_t x) { return (x + 255) & ~(size_t)255; }

extern "C" void kernel_launch(void* const* d_in, const int* in_sizes, int n_in,
                              void* d_out, int out_size, void* d_ws, size_t ws_size,
                              hipStream_t stream) {
    const float* x      = (const float*)d_in[0];
    const int*   ei     = (const int*)d_in[1];
    const int*   batch  = (const int*)d_in[2];
    const float* embW   = (const float*)d_in[3];
    const float* embB   = (const float*)d_in[4];
    const float* g1W    = (const float*)d_in[5];
    const float* g1as   = (const float*)d_in[6];
    const float* g1ad   = (const float*)d_in[7];
    const float* g1b    = (const float*)d_in[8];
    const float* g2W    = (const float*)d_in[9];
    const float* g2as   = (const float*)d_in[10];
    const float* g2ad   = (const float*)d_in[11];
    const float* g2b    = (const float*)d_in[12];
    const float* fc1W   = (const float*)d_in[13];
    const float* fc1b   = (const float*)d_in[14];
    const float* fc2W   = (const float*)d_in[15];
    const float* fc2b   = (const float*)d_in[16];
    const float* fc3W   = (const float*)d_in[17];
    const float* fc3b   = (const float*)d_in[18];
    float* out = (float*)d_out;

    const int N  = in_sizes[0] / NODE_DIM;   // 200000
    const int E  = in_sizes[1] / 2;          // 1200000
    const int G  = out_size;                 // 2048
    const int NH = N * HD;
    const int Es = (E + NPART - 1) / NPART;  // edges per slice

    char* ws = (char*)d_ws;
    float*  bufA    = (float*)ws;  ws += align256((size_t)NH * 4);
    __half* bufB    = (__half*)ws; ws += align256((size_t)NH * 2);
    float*  as_buf  = (float*)ws;  ws += align256((size_t)N * 4);
    float*  ad_buf  = (float*)ws;  ws += align256((size_t)N * 4);
    int*    deg     = (int*)ws;    ws += align256((size_t)NPART * N * 4);
    int*    off_sl  = (int*)ws;    ws += align256((size_t)NPART * (N + 1) * 4);
    int*    cursor  = (int*)ws;    ws += align256((size_t)NPART * N * 4);
    int*    blksum  = (int*)ws;    ws += align256((size_t)NPART * SCAN_B * 4);
    int*    csr_sl  = (int*)ws;    ws += align256((size_t)NPART * Es * 4);
    int*    csr_fin = (int*)ws;    ws += align256((size_t)E * 4);
    int*    off_tot = (int*)ws;    ws += align256((size_t)(N + 1) * 4);

    const int B = 256;
    dim3 blk(B);
    dim3 gr_gemm((N + GT - 1) / GT);                 // 64-node tiles
    dim3 gr_gath(((N + 3) / 4 * 64 + B - 1) / B);    // wave-per-4-nodes
    dim3 gr_slice(NPART * ((Es + B * EPT - 1) / (B * EPT)));  // edge-sliced, EPT/thread
    dim3 gr_n((N + B - 1) / B);
    const int nb = (N + SCAN_B - 1) / SCAN_B;

    // ---- CSR build: 8 sliced CSRs (XCD-local) then merge to one CSR
    zero_deg_k<<<dim3((NPART * N + B - 1) / B), blk, 0, stream>>>(deg, NPART * N);
    hist_k<<<gr_slice, blk, 0, stream>>>(ei, deg, E, Es, N);
    scan1_k<<<dim3(nb, NPART), dim3(SCAN_B), 0, stream>>>(deg, off_sl, blksum, N, nb);
    scan2_k<<<dim3(NPART), dim3(SCAN_B), 0, stream>>>(blksum, nb);
    scan3_k<<<dim3((N + B - 1) / B, NPART), blk, 0, stream>>>(off_sl, deg, blksum, cursor, N, nb);
    fill_csr_k<<<gr_slice, blk, 0, stream>>>(ei, cursor, csr_sl, E, Es, N);
    merge_k<<<gr_n, blk, 0, stream>>>(off_sl, csr_sl, csr_fin, off_tot, N, Es);

    // ======== GAT layer 1 (embed fused into the gemm) ========
    gemm_alpha_k<true><<<gr_gemm, blk, 0, stream>>>(x, embW, embB, g1W, g1as, g1ad,
                                                    bufB, as_buf, ad_buf, N);
    gather_k<true><<<gr_gath, blk, 0, stream>>>(off_tot, csr_fin, as_buf, ad_buf, bufB,
                                                g1b, bufA, N);

    // ======== GAT layer 2 ========
    gemm_alpha_k<false><<<gr_gemm, blk, 0, stream>>>(bufA, nullptr, nullptr, g2W,
                                                     g2as, g2ad, bufB, as_buf, ad_buf, N);
    gather_k<false><<<gr_gath, blk, 0, stream>>>(off_tot, csr_fin, as_buf, ad_buf, bufB,
                                                 nullptr, bufA, N);

    // ---- pooling + MLP (g2 bias applied here)
    pool_mlp_k<<<dim3(G), dim3(64), 0, stream>>>(bufA, g2b, batch, N,
                                                 fc1W, fc1b, fc2W, fc2b, fc3W, fc3b, out);
}

// Round 15
// 401.535 us; speedup vs baseline: 1.0622x; 1.0622x over previous
//
#include <hip/hip_runtime.h>
#include <hip/hip_bf16.h>
#include <hip/hip_fp16.h>

#define HD 64
#define NODE_DIM 5
#define NEG_SLOPE 0.2f
#define SCAN_B 1024
#define GT 64       // gemm node-tile per block
#define BSH 9       // bucket shift: 512 nodes/bucket
#define NBMAX 512   // static bucket array cap (N<=262144)
#define EPB 8       // edges per thread in bucket kernels

// Block = 64-node tile. W (64x64) and h-tile (64x65 padded) staged in LDS.
// Thread = (node-group, dim-quad): computes 4 nodes x 4 dims. k-loop unroll
// bounded to 8 (full unroll spilled at VGPR=256 in round 5).
// EMBED: h0 = x@embW+embB built directly in LDS. hout stored fp16 (halves the
// gather's random-read traffic); alphas computed from the fp32 accumulator
// BEFORE rounding so attention logits are exact.
template <bool EMBED>
__global__ __launch_bounds__(256) void gemm_alpha_k(
    const float* __restrict__ hin, const float* __restrict__ embW,
    const float* __restrict__ embB, const float* __restrict__ W,
    const float* __restrict__ asrc, const float* __restrict__ adst,
    __half* __restrict__ hout, float* __restrict__ alpha_s,
    float* __restrict__ alpha_d, int N) {
    __shared__ float hs[GT][HD + 1];   // 64 x 65 (pad breaks bank aliasing)
    __shared__ float Ws[HD * HD];      // 64 x 64
    __shared__ float xe[GT * NODE_DIM];      // EMBED: x tile (320)
    __shared__ float we[NODE_DIM * HD + HD]; // EMBED: embW + embB (384)
    const int t = threadIdx.x;
    const int n0 = blockIdx.x * GT;
    if (n0 >= N) return;
    const int rem = N - n0;

    // stage W: 4096 floats = 1024 float4, coalesced
    {
        const float4* w4 = (const float4*)W;
        float4* s4 = (float4*)Ws;
#pragma unroll
        for (int j = 0; j < 4; j++) s4[t + 256 * j] = w4[t + 256 * j];
    }
    if (EMBED) {
        // stage x tile (64x5=320), embW (5x64) + embB (64) = 384 — strided
        for (int j = t; j < GT * NODE_DIM; j += 256)
            xe[j] = (j < rem * NODE_DIM) ? hin[(size_t)n0 * NODE_DIM + j] : 0.0f;
        for (int j = t; j < NODE_DIM * HD + HD; j += 256)
            we[j] = (j < NODE_DIM * HD) ? embW[j] : embB[j - NODE_DIM * HD];
        __syncthreads();
        // build h0 tile: 4 threads per row, 16 dims each
        int r = t >> 2, d0 = (t & 3) * 16;
#pragma unroll
        for (int jj = 0; jj < 16; jj++) {
            int d = d0 + jj;
            float acc = we[NODE_DIM * HD + d];
#pragma unroll
            for (int k = 0; k < NODE_DIM; k++)
                acc = fmaf(xe[r * NODE_DIM + k], we[k * HD + d], acc);
            hs[r][d] = (r < rem) ? acc : 0.0f;
        }
    } else {
        // stage h tile: coalesced float4 read, padded scalar write
        const float4* g4 = (const float4*)(hin + (size_t)n0 * HD);
#pragma unroll
        for (int j = 0; j < 4; j++) {
            int idx = t + 256 * j;
            int row = idx >> 4, c4 = idx & 15;
            float4 v = {0, 0, 0, 0};
            if (row < rem) v = g4[idx];
            hs[row][c4 * 4 + 0] = v.x;
            hs[row][c4 * 4 + 1] = v.y;
            hs[row][c4 * 4 + 2] = v.z;
            hs[row][c4 * 4 + 3] = v.w;
        }
    }
    __syncthreads();

    const int dq = t & 15;    // dim quad (dims 4*dq..4*dq+3)
    const int grp = t >> 4;   // node group (nodes 4*grp..4*grp+3)
    float4 acc[4];
#pragma unroll
    for (int i = 0; i < 4; i++) acc[i] = {0, 0, 0, 0};

#pragma unroll 8
    for (int k = 0; k < 64; k++) {
        float4 w4 = *(const float4*)(Ws + k * HD + dq * 4);
#pragma unroll
        for (int i = 0; i < 4; i++) {
            float hv = hs[grp * 4 + i][k];
            acc[i].x = fmaf(hv, w4.x, acc[i].x);
            acc[i].y = fmaf(hv, w4.y, acc[i].y);
            acc[i].z = fmaf(hv, w4.z, acc[i].z);
            acc[i].w = fmaf(hv, w4.w, acc[i].w);
        }
    }

    // epilogue: store hout (fp16, 8B) + 16-lane reduce for alpha_s/alpha_d
    float4 a4 = ((const float4*)asrc)[dq];
    float4 b4 = ((const float4*)adst)[dq];
#pragma unroll
    for (int i = 0; i < 4; i++) {
        int n = n0 + grp * 4 + i;
        if (n >= N) break;
        short4 s;
        s.x = __half_as_short(__float2half_rn(acc[i].x));
        s.y = __half_as_short(__float2half_rn(acc[i].y));
        s.z = __half_as_short(__float2half_rn(acc[i].z));
        s.w = __half_as_short(__float2half_rn(acc[i].w));
        ((short4*)hout)[(size_t)n * 16 + dq] = s;
        float ps = acc[i].x * a4.x + acc[i].y * a4.y + acc[i].z * a4.z + acc[i].w * a4.w;
        float pd = acc[i].x * b4.x + acc[i].y * b4.y + acc[i].z * b4.z + acc[i].w * b4.w;
#pragma unroll
        for (int off = 8; off; off >>= 1) {   // reduce across the 16-lane group
            ps += __shfl_xor(ps, off);
            pd += __shfl_xor(pd, off);
        }
        if (dq == 0) {
            alpha_s[n] = ps;
            alpha_d[n] = pd;
        }
    }
}

// ------------- bucket-partitioned CSR build (no self-loops in CSR) ---------
// Rounds 4-14 showed dst-scatter CSR fill is stuck at ~8x write amplification:
// same-dst writes are spread across the kernel lifetime so every csrsrc line
// is evicted ~8x before it fills. Fix: coarse-sort edges by dst-bucket
// (dst>>9, 512 nodes/bucket) first. Pass A = classic block radix partition
// (LDS hist -> one reservation atomic per block x bucket -> scatter into
// per-bucket windows; active window = ~NB x 64B, L2-resident -> amp ~1).
// Pass B reads bucketed pairs so deg/cursor/csrsrc windows are hot & packed.

__global__ void zero_k(int* __restrict__ p, int total) {
    int i = blockIdx.x * blockDim.x + threadIdx.x;
    if (i < total) p[i] = 0;
}

// bucket histogram: LDS-aggregated, one global atomic per (block,bucket)
__global__ __launch_bounds__(256) void bucket_hist_k(
    const int* __restrict__ ei, int* __restrict__ bcnt, int E) {
    __shared__ int lcnt[NBMAX];
    for (int b = threadIdx.x; b < NBMAX; b += 256) lcnt[b] = 0;
    __syncthreads();
    int jb = blockIdx.x * (256 * EPB) + threadIdx.x;
#pragma unroll
    for (int u = 0; u < EPB; u++) {
        int j = jb + u * 256;
        if (j < E) {
            int dst = __builtin_nontemporal_load(&ei[E + j]);
            atomicAdd(&lcnt[dst >> BSH], 1);
        }
    }
    __syncthreads();
    for (int b = threadIdx.x; b < NBMAX; b += 256)
        if (lcnt[b]) atomicAdd(&bcnt[b], lcnt[b]);
}

// single block: exclusive scan of bcnt[NB] -> bcur (partition cursors)
__global__ void bucket_scan_k(const int* __restrict__ bcnt, int* __restrict__ bcur, int NB) {
    __shared__ int s[NBMAX];
    int t = threadIdx.x;
    int v = (t < NB) ? bcnt[t] : 0;
    s[t] = v;
    __syncthreads();
#pragma unroll
    for (int o = 1; o < NBMAX; o <<= 1) {
        int tv = (t >= o) ? s[t - o] : 0;
        __syncthreads();
        s[t] += tv;
        __syncthreads();
    }
    if (t < NB) bcur[t] = s[t] - v;  // exclusive
}

// block radix partition: scatter (src,dst) pairs into bucket windows
__global__ __launch_bounds__(256) void partition_k(
    const int* __restrict__ ei, int* __restrict__ bcur,
    int2* __restrict__ bpair, int E) {
    __shared__ int lcnt[NBMAX], lbase[NBMAX];
    int dst[EPB], src[EPB];
    int jb = blockIdx.x * (256 * EPB) + threadIdx.x;
#pragma unroll
    for (int u = 0; u < EPB; u++) {
        int j = jb + u * 256;
        if (j < E) {
            dst[u] = __builtin_nontemporal_load(&ei[E + j]);
            src[u] = __builtin_nontemporal_load(&ei[j]);
        } else dst[u] = -1;
    }
    for (int b = threadIdx.x; b < NBMAX; b += 256) lcnt[b] = 0;
    __syncthreads();
#pragma unroll
    for (int u = 0; u < EPB; u++)
        if (dst[u] >= 0) atomicAdd(&lcnt[dst[u] >> BSH], 1);
    __syncthreads();
    for (int b = threadIdx.x; b < NBMAX; b += 256) {
        int c = lcnt[b];
        lbase[b] = c ? atomicAdd(&bcur[b], c) : 0;
        lcnt[b] = 0;
    }
    __syncthreads();
#pragma unroll
    for (int u = 0; u < EPB; u++) {
        if (dst[u] >= 0) {
            int b = dst[u] >> BSH;
            int o = atomicAdd(&lcnt[b], 1);
            int2 pr; pr.x = src[u]; pr.y = dst[u];
            bpair[lbase[b] + o] = pr;
        }
    }
}

// deg histogram from bucketed pairs: dst-local -> deg window hot in L2
__global__ void deg_hist_k(const int2* __restrict__ bpair, int* __restrict__ deg, int E) {
    int j = blockIdx.x * blockDim.x + threadIdx.x;
    if (j >= E) return;
    atomicAdd(&deg[bpair[j].y], 1);
}

__global__ void scan1_k(const int* __restrict__ deg, int* __restrict__ off,
                        int* __restrict__ blksum, int N) {
    __shared__ int s[SCAN_B];
    int gid = blockIdx.x * SCAN_B + threadIdx.x;
    int v = (gid < N) ? deg[gid] : 0;
    s[threadIdx.x] = v;
    __syncthreads();
#pragma unroll
    for (int o = 1; o < SCAN_B; o <<= 1) {
        int t = (threadIdx.x >= o) ? s[threadIdx.x - o] : 0;
        __syncthreads();
        s[threadIdx.x] += t;
        __syncthreads();
    }
    if (gid < N) off[gid + 1] = s[threadIdx.x];
    if (threadIdx.x == SCAN_B - 1) blksum[blockIdx.x] = s[SCAN_B - 1];
}

__global__ void scan2_k(int* __restrict__ blksum, int nb) {
    __shared__ int s[SCAN_B];
    int v = ((int)threadIdx.x < nb) ? blksum[threadIdx.x] : 0;
    s[threadIdx.x] = v;
    __syncthreads();
#pragma unroll
    for (int o = 1; o < SCAN_B; o <<= 1) {
        int t = (threadIdx.x >= o) ? s[threadIdx.x - o] : 0;
        __syncthreads();
        s[threadIdx.x] += t;
        __syncthreads();
    }
    if ((int)threadIdx.x < nb) blksum[threadIdx.x] = s[threadIdx.x] - v;  // exclusive
}

__global__ void scan3_k(int* __restrict__ off, const int* __restrict__ deg,
                        const int* __restrict__ blksum, int* __restrict__ cursor, int N) {
    int gid = blockIdx.x * blockDim.x + threadIdx.x;
    if (gid >= N) return;
    int inc = off[gid + 1] + blksum[gid >> 10];
    off[gid + 1] = inc;
    cursor[gid] = inc - deg[gid];
    if (gid == 0) off[0] = 0;
}

// fill from bucketed pairs: cursor + csrsrc windows hot; lines packed once
__global__ void fill2_k(const int2* __restrict__ bpair, int* __restrict__ cursor,
                        int* __restrict__ csr_src, int E) {
    int j = blockIdx.x * blockDim.x + threadIdx.x;
    if (j >= E) return;
    int2 pr = bpair[j];
    int pos = atomicAdd(&cursor[pr.y], 1);
    csr_src[pos] = pr.x;
}

// ---------------- fused attention + weighted gather ----------------
// wave = 4 nodes; 16 lanes/node; lane holds 4 dims (fp16, 8B load).
// Single contiguous CSR segment; self-loop inline. w = exp(leaky(...)) inline
// (softmax shift-invariance; logits O(±6), fp32-safe). Accumulation in fp32.
template <bool BR>
__global__ __launch_bounds__(256) void gather_k(
    const int* __restrict__ off, const int* __restrict__ csr_src,
    const float* __restrict__ as, const float* __restrict__ ad,
    const __half* __restrict__ h, const float* __restrict__ bias,
    float* __restrict__ out, int N) {
    int tid = blockIdx.x * blockDim.x + threadIdx.x;
    int wv = tid >> 6;
    int lane = threadIdx.x & 63;
    int grp = lane >> 4;
    int l16 = lane & 15;
    int n = wv * 4 + grp;
    if (n >= N) return;
    int s0 = off[n], s1 = off[n + 1];
    float adv = ad[n];
    const short4* h4 = (const short4*)h;

    // self-loop: src = n
    float e = as[n] + adv;
    e = (e >= 0.0f) ? e : NEG_SLOPE * e;
    float wsl = __expf(e);
    float l0 = wsl, l1 = 0.0f;
    short4 hvs = h4[(size_t)n * 16 + l16];
    float4 acc0, acc1 = {0, 0, 0, 0};
    acc0.x = wsl * __half2float(__short_as_half(hvs.x));
    acc0.y = wsl * __half2float(__short_as_half(hvs.y));
    acc0.z = wsl * __half2float(__short_as_half(hvs.z));
    acc0.w = wsl * __half2float(__short_as_half(hvs.w));

    int i = s0;
    for (; i + 2 <= s1; i += 2) {
        int src0 = csr_src[i], src1 = csr_src[i + 1];
        float e0 = as[src0] + adv;
        float e1 = as[src1] + adv;
        short4 hv0 = h4[(size_t)src0 * 16 + l16];
        short4 hv1 = h4[(size_t)src1 * 16 + l16];
        e0 = (e0 >= 0.0f) ? e0 : NEG_SLOPE * e0;
        e1 = (e1 >= 0.0f) ? e1 : NEG_SLOPE * e1;
        float w0 = __expf(e0), w1 = __expf(e1);
        l0 += w0; l1 += w1;
        acc0.x = fmaf(w0, __half2float(__short_as_half(hv0.x)), acc0.x);
        acc0.y = fmaf(w0, __half2float(__short_as_half(hv0.y)), acc0.y);
        acc0.z = fmaf(w0, __half2float(__short_as_half(hv0.z)), acc0.z);
        acc0.w = fmaf(w0, __half2float(__short_as_half(hv0.w)), acc0.w);
        acc1.x = fmaf(w1, __half2float(__short_as_half(hv1.x)), acc1.x);
        acc1.y = fmaf(w1, __half2float(__short_as_half(hv1.y)), acc1.y);
        acc1.z = fmaf(w1, __half2float(__short_as_half(hv1.z)), acc1.z);
        acc1.w = fmaf(w1, __half2float(__short_as_half(hv1.w)), acc1.w);
    }
    if (i < s1) {
        int src0 = csr_src[i];
        float e0 = as[src0] + adv;
        short4 hv0 = h4[(size_t)src0 * 16 + l16];
        e0 = (e0 >= 0.0f) ? e0 : NEG_SLOPE * e0;
        float w0 = __expf(e0);
        l0 += w0;
        acc0.x = fmaf(w0, __half2float(__short_as_half(hv0.x)), acc0.x);
        acc0.y = fmaf(w0, __half2float(__short_as_half(hv0.y)), acc0.y);
        acc0.z = fmaf(w0, __half2float(__short_as_half(hv0.z)), acc0.z);
        acc0.w = fmaf(w0, __half2float(__short_as_half(hv0.w)), acc0.w);
    }
    float inv = 1.0f / (l0 + l1 + 1e-16f);
    float4 r;
    r.x = (acc0.x + acc1.x) * inv;
    r.y = (acc0.y + acc1.y) * inv;
    r.z = (acc0.z + acc1.z) * inv;
    r.w = (acc0.w + acc1.w) * inv;
    if (BR) {
        float4 b = ((const float4*)bias)[l16];
        r.x = fmaxf(r.x + b.x, 0.0f);
        r.y = fmaxf(r.y + b.y, 0.0f);
        r.z = fmaxf(r.z + b.z, 0.0f);
        r.w = fmaxf(r.w + b.w, 0.0f);
    }
    ((float4*)out)[(size_t)n * 16 + l16] = r;
}

// one wave per graph: pooling + 3-layer MLP
__global__ void pool_mlp_k(const float* __restrict__ hfin, const float* __restrict__ hb,
                           const int* __restrict__ batch, int N,
                           const float* __restrict__ fc1W, const float* __restrict__ fc1b,
                           const float* __restrict__ fc2W, const float* __restrict__ fc2b,
                           const float* __restrict__ fc3W, const float* __restrict__ fc3b,
                           float* __restrict__ out) {
    __shared__ float lds[192];
    int g = blockIdx.x;
    int lane = threadIdx.x;
    int lo = 0, hi = N;
    while (lo < hi) { int mid = (lo + hi) >> 1; if (batch[mid] < g) lo = mid + 1; else hi = mid; }
    int start = lo;
    lo = start; hi = N;
    while (lo < hi) { int mid = (lo + hi) >> 1; if (batch[mid] < g + 1) lo = mid + 1; else hi = mid; }
    int end = lo;
    float bias = hb[lane];
    float sum = 0.0f, mx = -INFINITY;
    for (int n = start; n < end; n++) {
        float v = hfin[(size_t)n * HD + lane] + bias;
        sum += v;
        mx = fmaxf(mx, v);
    }
    int cnt = end - start;
    float mean = (cnt > 0) ? sum / (float)cnt : 0.0f;
    if (cnt == 0) mx = 0.0f;
    lds[lane] = mean;
    lds[64 + lane] = mx;
    __syncthreads();
    float o1 = fc1b[lane];
    for (int k = 0; k < 128; k++) o1 += lds[k] * fc1W[k * 64 + lane];
    o1 = fmaxf(o1, 0.0f);
    __syncthreads();
    lds[lane] = o1;
    __syncthreads();
    if (lane < 32) {
        float o2 = fc2b[lane];
        for (int k = 0; k < 64; k++) o2 += lds[k] * fc2W[k * 32 + lane];
        lds[128 + lane] = fmaxf(o2, 0.0f);
    }
    __syncthreads();
    if (lane == 0) {
        float o3 = fc3b[0];
        for (int k = 0; k < 32; k++) o3 += lds[128 + k] * fc3W[k];
        out[g] = o3;
    }
}

static inline size_t align256(size_t x) { return (x + 255) & ~(size_t)255; }

extern "C" void kernel_launch(void* const* d_in, const int* in_sizes, int n_in,
                              void* d_out, int out_size, void* d_ws, size_t ws_size,
                              hipStream_t stream) {
    const float* x      = (const float*)d_in[0];
    const int*   ei     = (const int*)d_in[1];
    const int*   batch  = (const int*)d_in[2];
    const float* embW   = (const float*)d_in[3];
    const float* embB   = (const float*)d_in[4];
    const float* g1W    = (const float*)d_in[5];
    const float* g1as   = (const float*)d_in[6];
    const float* g1ad   = (const float*)d_in[7];
    const float* g1b    = (const float*)d_in[8];
    const float* g2W    = (const float*)d_in[9];
    const float* g2as   = (const float*)d_in[10];
    const float* g2ad   = (const float*)d_in[11];
    const float* g2b    = (const float*)d_in[12];
    const float* fc1W   = (const float*)d_in[13];
    const float* fc1b   = (const float*)d_in[14];
    const float* fc2W   = (const float*)d_in[15];
    const float* fc2b   = (const float*)d_in[16];
    const float* fc3W   = (const float*)d_in[17];
    const float* fc3b   = (const float*)d_in[18];
    float* out = (float*)d_out;

    const int N  = in_sizes[0] / NODE_DIM;   // 200000
    const int E  = in_sizes[1] / 2;          // 1200000
    const int G  = out_size;                 // 2048
    const int NH = N * HD;
    const int NB = (N + (1 << BSH) - 1) >> BSH;  // 391 buckets

    char* ws = (char*)d_ws;
    float*  bufA    = (float*)ws;  ws += align256((size_t)NH * 4);
    __half* bufB    = (__half*)ws; ws += align256((size_t)NH * 2);
    float*  as_buf  = (float*)ws;  ws += align256((size_t)N * 4);
    float*  ad_buf  = (float*)ws;  ws += align256((size_t)N * 4);
    int*    deg     = (int*)ws;    ws += align256((size_t)N * 4);
    int*    off     = (int*)ws;    ws += align256((size_t)(N + 1) * 4);
    int*    cursor  = (int*)ws;    ws += align256((size_t)N * 4);
    int*    blksum  = (int*)ws;    ws += align256((size_t)SCAN_B * 4);
    int*    bcnt    = (int*)ws;    ws += align256((size_t)NBMAX * 4);
    int*    bcur    = (int*)ws;    ws += align256((size_t)NBMAX * 4);
    int2*   bpair   = (int2*)ws;   ws += align256((size_t)E * 8);
    int*    csrsrc  = (int*)ws;    ws += align256((size_t)E * 4);

    const int B = 256;
    dim3 blk(B);
    dim3 gr_gemm((N + GT - 1) / GT);                 // 64-node tiles
    dim3 gr_gath(((N + 3) / 4 * 64 + B - 1) / B);    // wave-per-4-nodes
    dim3 gr_epb((E + B * EPB - 1) / (B * EPB));      // bucket kernels
    dim3 gr_e((E + B - 1) / B);                      // per-edge kernels
    dim3 gr_n((N + B - 1) / B);
    const int nb = (N + SCAN_B - 1) / SCAN_B;

    // ---- CSR build: bucket partition (pass A) then hot-window CSR (pass B)
    zero_k<<<dim3((N + B - 1) / B), blk, 0, stream>>>(deg, N);
    zero_k<<<dim3(2), blk, 0, stream>>>(bcnt, NBMAX);
    bucket_hist_k<<<gr_epb, blk, 0, stream>>>(ei, bcnt, E);
    bucket_scan_k<<<dim3(1), dim3(NBMAX), 0, stream>>>(bcnt, bcur, NB);
    partition_k<<<gr_epb, blk, 0, stream>>>(ei, bcur, bpair, E);
    deg_hist_k<<<gr_e, blk, 0, stream>>>(bpair, deg, E);
    scan1_k<<<dim3(nb), dim3(SCAN_B), 0, stream>>>(deg, off, blksum, N);
    scan2_k<<<dim3(1), dim3(SCAN_B), 0, stream>>>(blksum, nb);
    scan3_k<<<gr_n, blk, 0, stream>>>(off, deg, blksum, cursor, N);
    fill2_k<<<gr_e, blk, 0, stream>>>(bpair, cursor, csrsrc, E);

    // ======== GAT layer 1 (embed fused into the gemm) ========
    gemm_alpha_k<true><<<gr_gemm, blk, 0, stream>>>(x, embW, embB, g1W, g1as, g1ad,
                                                    bufB, as_buf, ad_buf, N);
    gather_k<true><<<gr_gath, blk, 0, stream>>>(off, csrsrc, as_buf, ad_buf, bufB,
                                                g1b, bufA, N);

    // ======== GAT layer 2 ========
    gemm_alpha_k<false><<<gr_gemm, blk, 0, stream>>>(bufA, nullptr, nullptr, g2W,
                                                     g2as, g2ad, bufB, as_buf, ad_buf, N);
    gather_k<false><<<gr_gath, blk, 0, stream>>>(off, csrsrc, as_buf, ad_buf, bufB,
                                                 nullptr, bufA, N);

    // ---- pooling + MLP (g2 bias applied here)
    pool_mlp_k<<<dim3(G), dim3(64), 0, stream>>>(bufA, g2b, batch, N,
                                                 fc1W, fc1b, fc2W, fc2b, fc3W, fc3b, out);
}

// Round 16
// 384.012 us; speedup vs baseline: 1.1107x; 1.0456x over previous
//
#include <hip/hip_runtime.h>
#include <hip/hip_bf16.h>
#include <hip/hip_fp16.h>

#define HD 64
#define NODE_DIM 5
#define NEG_SLOPE 0.2f
#define SCAN_B 1024
#define GT 64       // gemm node-tile per block
#define BSH 9       // bucket shift: 512 nodes/bucket
#define NBMAX 512   // static bucket array cap (N<=262144)
#define EPB 8       // edges per thread in bucket kernels

// Block = 64-node tile. W (64x64) and h-tile (64x65 padded) staged in LDS.
// Thread = (node-group, dim-quad): computes 4 nodes x 4 dims. k-loop unroll
// bounded to 8 (full unroll spilled at VGPR=256 in round 5).
// EMBED: h0 = x@embW+embB built directly in LDS. hout stored fp16 (halves the
// gather's random-read traffic); alphas computed from the fp32 accumulator
// BEFORE rounding so attention logits are exact.
template <bool EMBED>
__global__ __launch_bounds__(256) void gemm_alpha_k(
    const float* __restrict__ hin, const float* __restrict__ embW,
    const float* __restrict__ embB, const float* __restrict__ W,
    const float* __restrict__ asrc, const float* __restrict__ adst,
    __half* __restrict__ hout, float* __restrict__ alpha_s,
    float* __restrict__ alpha_d, int N) {
    __shared__ float hs[GT][HD + 1];   // 64 x 65 (pad breaks bank aliasing)
    __shared__ float Ws[HD * HD];      // 64 x 64
    __shared__ float xe[GT * NODE_DIM];      // EMBED: x tile (320)
    __shared__ float we[NODE_DIM * HD + HD]; // EMBED: embW + embB (384)
    const int t = threadIdx.x;
    const int n0 = blockIdx.x * GT;
    if (n0 >= N) return;
    const int rem = N - n0;

    // stage W: 4096 floats = 1024 float4, coalesced
    {
        const float4* w4 = (const float4*)W;
        float4* s4 = (float4*)Ws;
#pragma unroll
        for (int j = 0; j < 4; j++) s4[t + 256 * j] = w4[t + 256 * j];
    }
    if (EMBED) {
        // stage x tile (64x5=320), embW (5x64) + embB (64) = 384 — strided
        for (int j = t; j < GT * NODE_DIM; j += 256)
            xe[j] = (j < rem * NODE_DIM) ? hin[(size_t)n0 * NODE_DIM + j] : 0.0f;
        for (int j = t; j < NODE_DIM * HD + HD; j += 256)
            we[j] = (j < NODE_DIM * HD) ? embW[j] : embB[j - NODE_DIM * HD];
        __syncthreads();
        // build h0 tile: 4 threads per row, 16 dims each
        int r = t >> 2, d0 = (t & 3) * 16;
#pragma unroll
        for (int jj = 0; jj < 16; jj++) {
            int d = d0 + jj;
            float acc = we[NODE_DIM * HD + d];
#pragma unroll
            for (int k = 0; k < NODE_DIM; k++)
                acc = fmaf(xe[r * NODE_DIM + k], we[k * HD + d], acc);
            hs[r][d] = (r < rem) ? acc : 0.0f;
        }
    } else {
        // stage h tile: coalesced float4 read, padded scalar write
        const float4* g4 = (const float4*)(hin + (size_t)n0 * HD);
#pragma unroll
        for (int j = 0; j < 4; j++) {
            int idx = t + 256 * j;
            int row = idx >> 4, c4 = idx & 15;
            float4 v = {0, 0, 0, 0};
            if (row < rem) v = g4[idx];
            hs[row][c4 * 4 + 0] = v.x;
            hs[row][c4 * 4 + 1] = v.y;
            hs[row][c4 * 4 + 2] = v.z;
            hs[row][c4 * 4 + 3] = v.w;
        }
    }
    __syncthreads();

    const int dq = t & 15;    // dim quad (dims 4*dq..4*dq+3)
    const int grp = t >> 4;   // node group (nodes 4*grp..4*grp+3)
    float4 acc[4];
#pragma unroll
    for (int i = 0; i < 4; i++) acc[i] = {0, 0, 0, 0};

#pragma unroll 8
    for (int k = 0; k < 64; k++) {
        float4 w4 = *(const float4*)(Ws + k * HD + dq * 4);
#pragma unroll
        for (int i = 0; i < 4; i++) {
            float hv = hs[grp * 4 + i][k];
            acc[i].x = fmaf(hv, w4.x, acc[i].x);
            acc[i].y = fmaf(hv, w4.y, acc[i].y);
            acc[i].z = fmaf(hv, w4.z, acc[i].z);
            acc[i].w = fmaf(hv, w4.w, acc[i].w);
        }
    }

    // epilogue: store hout (fp16, 8B) + 16-lane reduce for alpha_s/alpha_d
    float4 a4 = ((const float4*)asrc)[dq];
    float4 b4 = ((const float4*)adst)[dq];
#pragma unroll
    for (int i = 0; i < 4; i++) {
        int n = n0 + grp * 4 + i;
        if (n >= N) break;
        short4 s;
        s.x = __half_as_short(__float2half_rn(acc[i].x));
        s.y = __half_as_short(__float2half_rn(acc[i].y));
        s.z = __half_as_short(__float2half_rn(acc[i].z));
        s.w = __half_as_short(__float2half_rn(acc[i].w));
        ((short4*)hout)[(size_t)n * 16 + dq] = s;
        float ps = acc[i].x * a4.x + acc[i].y * a4.y + acc[i].z * a4.z + acc[i].w * a4.w;
        float pd = acc[i].x * b4.x + acc[i].y * b4.y + acc[i].z * b4.z + acc[i].w * b4.w;
#pragma unroll
        for (int off = 8; off; off >>= 1) {   // reduce across the 16-lane group
            ps += __shfl_xor(ps, off);
            pd += __shfl_xor(pd, off);
        }
        if (dq == 0) {
            alpha_s[n] = ps;
            alpha_d[n] = pd;
        }
    }
}

// ------------- bucket-partitioned CSR build (no self-loops in CSR) ---------
// Rounds 4-14: dst-scatter CSR fill is stuck at ~8x write amplification
// because same-dst writes are spread across the kernel lifetime. Fix (R15,
// confirmed): coarse-sort edges by dst-bucket (dst>>9) first; pass B's
// deg/cursor/csrsrc windows are then hot in L2 and lines packed once.

__global__ void zero_k(int* __restrict__ p, int total) {
    int i = blockIdx.x * blockDim.x + threadIdx.x;
    if (i < total) p[i] = 0;
}

// bucket histogram: LDS-aggregated, one global atomic per (block,bucket)
__global__ __launch_bounds__(256) void bucket_hist_k(
    const int* __restrict__ ei, int* __restrict__ bcnt, int E) {
    __shared__ int lcnt[NBMAX];
    for (int b = threadIdx.x; b < NBMAX; b += 256) lcnt[b] = 0;
    __syncthreads();
    int jb = blockIdx.x * (256 * EPB) + threadIdx.x;
#pragma unroll
    for (int u = 0; u < EPB; u++) {
        int j = jb + u * 256;
        if (j < E) {
            int dst = __builtin_nontemporal_load(&ei[E + j]);
            atomicAdd(&lcnt[dst >> BSH], 1);
        }
    }
    __syncthreads();
    for (int b = threadIdx.x; b < NBMAX; b += 256)
        if (lcnt[b]) atomicAdd(&bcnt[b], lcnt[b]);
}

// single block: exclusive scan of bcnt[NB] -> bcur (partition cursors)
__global__ void bucket_scan_k(const int* __restrict__ bcnt, int* __restrict__ bcur, int NB) {
    __shared__ int s[NBMAX];
    int t = threadIdx.x;
    int v = (t < NB) ? bcnt[t] : 0;
    s[t] = v;
    __syncthreads();
#pragma unroll
    for (int o = 1; o < NBMAX; o <<= 1) {
        int tv = (t >= o) ? s[t - o] : 0;
        __syncthreads();
        s[t] += tv;
        __syncthreads();
    }
    if (t < NB) bcur[t] = s[t] - v;  // exclusive
}

// block radix partition: scatter (src,dst) pairs into bucket windows
__global__ __launch_bounds__(256) void partition_k(
    const int* __restrict__ ei, int* __restrict__ bcur,
    int2* __restrict__ bpair, int E) {
    __shared__ int lcnt[NBMAX], lbase[NBMAX];
    int dst[EPB], src[EPB];
    int jb = blockIdx.x * (256 * EPB) + threadIdx.x;
#pragma unroll
    for (int u = 0; u < EPB; u++) {
        int j = jb + u * 256;
        if (j < E) {
            dst[u] = __builtin_nontemporal_load(&ei[E + j]);
            src[u] = __builtin_nontemporal_load(&ei[j]);
        } else dst[u] = -1;
    }
    for (int b = threadIdx.x; b < NBMAX; b += 256) lcnt[b] = 0;
    __syncthreads();
#pragma unroll
    for (int u = 0; u < EPB; u++)
        if (dst[u] >= 0) atomicAdd(&lcnt[dst[u] >> BSH], 1);
    __syncthreads();
    for (int b = threadIdx.x; b < NBMAX; b += 256) {
        int c = lcnt[b];
        lbase[b] = c ? atomicAdd(&bcur[b], c) : 0;
        lcnt[b] = 0;
    }
    __syncthreads();
#pragma unroll
    for (int u = 0; u < EPB; u++) {
        if (dst[u] >= 0) {
            int b = dst[u] >> BSH;
            int o = atomicAdd(&lcnt[b], 1);
            int2 pr; pr.x = src[u]; pr.y = dst[u];
            bpair[lbase[b] + o] = pr;
        }
    }
}

// deg histogram from bucketed pairs: dst-local -> deg window hot in L2
__global__ void deg_hist_k(const int2* __restrict__ bpair, int* __restrict__ deg, int E) {
    int j = blockIdx.x * blockDim.x + threadIdx.x;
    if (j >= E) return;
    atomicAdd(&deg[bpair[j].y], 1);
}

__global__ void scan1_k(const int* __restrict__ deg, int* __restrict__ off,
                        int* __restrict__ blksum, int N) {
    __shared__ int s[SCAN_B];
    int gid = blockIdx.x * SCAN_B + threadIdx.x;
    int v = (gid < N) ? deg[gid] : 0;
    s[threadIdx.x] = v;
    __syncthreads();
#pragma unroll
    for (int o = 1; o < SCAN_B; o <<= 1) {
        int t = (threadIdx.x >= o) ? s[threadIdx.x - o] : 0;
        __syncthreads();
        s[threadIdx.x] += t;
        __syncthreads();
    }
    if (gid < N) off[gid + 1] = s[threadIdx.x];
    if (threadIdx.x == SCAN_B - 1) blksum[blockIdx.x] = s[SCAN_B - 1];
}

__global__ void scan2_k(int* __restrict__ blksum, int nb) {
    __shared__ int s[SCAN_B];
    int v = ((int)threadIdx.x < nb) ? blksum[threadIdx.x] : 0;
    s[threadIdx.x] = v;
    __syncthreads();
#pragma unroll
    for (int o = 1; o < SCAN_B; o <<= 1) {
        int t = (threadIdx.x >= o) ? s[threadIdx.x - o] : 0;
        __syncthreads();
        s[threadIdx.x] += t;
        __syncthreads();
    }
    if ((int)threadIdx.x < nb) blksum[threadIdx.x] = s[threadIdx.x] - v;  // exclusive
}

__global__ void scan3_k(int* __restrict__ off, const int* __restrict__ deg,
                        const int* __restrict__ blksum, int* __restrict__ cursor, int N) {
    int gid = blockIdx.x * blockDim.x + threadIdx.x;
    if (gid >= N) return;
    int inc = off[gid + 1] + blksum[gid >> 10];
    off[gid + 1] = inc;
    cursor[gid] = inc - deg[gid];
    if (gid == 0) off[0] = 0;
}

// fill from bucketed pairs: cursor + csrsrc windows hot; lines packed once
__global__ void fill2_k(const int2* __restrict__ bpair, int* __restrict__ cursor,
                        int* __restrict__ csr_src, int E) {
    int j = blockIdx.x * blockDim.x + threadIdx.x;
    if (j >= E) return;
    int2 pr = bpair[j];
    int pos = atomicAdd(&cursor[pr.y], 1);
    csr_src[pos] = pr.x;
}

// ---------------- fused attention + weighted gather ----------------
// wave = 4 nodes; 16 lanes/node; lane holds 4 dims (fp16, 8B load).
// Single contiguous CSR segment; self-loop inline. w = exp(leaky(...)) inline
// (softmax shift-invariance; logits O(±6), fp32-safe). Accumulation in fp32.
template <bool BR>
__global__ __launch_bounds__(256) void gather_k(
    const int* __restrict__ off, const int* __restrict__ csr_src,
    const float* __restrict__ as, const float* __restrict__ ad,
    const __half* __restrict__ h, const float* __restrict__ bias,
    float* __restrict__ out, int N) {
    int tid = blockIdx.x * blockDim.x + threadIdx.x;
    int wv = tid >> 6;
    int lane = threadIdx.x & 63;
    int grp = lane >> 4;
    int l16 = lane & 15;
    int n = wv * 4 + grp;
    if (n >= N) return;
    int s0 = off[n], s1 = off[n + 1];
    float adv = ad[n];
    const short4* h4 = (const short4*)h;

    // self-loop: src = n
    float e = as[n] + adv;
    e = (e >= 0.0f) ? e : NEG_SLOPE * e;
    float wsl = __expf(e);
    float l0 = wsl, l1 = 0.0f;
    short4 hvs = h4[(size_t)n * 16 + l16];
    float4 acc0, acc1 = {0, 0, 0, 0};
    acc0.x = wsl * __half2float(__short_as_half(hvs.x));
    acc0.y = wsl * __half2float(__short_as_half(hvs.y));
    acc0.z = wsl * __half2float(__short_as_half(hvs.z));
    acc0.w = wsl * __half2float(__short_as_half(hvs.w));

    int i = s0;
    for (; i + 2 <= s1; i += 2) {
        int src0 = csr_src[i], src1 = csr_src[i + 1];
        float e0 = as[src0] + adv;
        float e1 = as[src1] + adv;
        short4 hv0 = h4[(size_t)src0 * 16 + l16];
        short4 hv1 = h4[(size_t)src1 * 16 + l16];
        e0 = (e0 >= 0.0f) ? e0 : NEG_SLOPE * e0;
        e1 = (e1 >= 0.0f) ? e1 : NEG_SLOPE * e1;
        float w0 = __expf(e0), w1 = __expf(e1);
        l0 += w0; l1 += w1;
        acc0.x = fmaf(w0, __half2float(__short_as_half(hv0.x)), acc0.x);
        acc0.y = fmaf(w0, __half2float(__short_as_half(hv0.y)), acc0.y);
        acc0.z = fmaf(w0, __half2float(__short_as_half(hv0.z)), acc0.z);
        acc0.w = fmaf(w0, __half2float(__short_as_half(hv0.w)), acc0.w);
        acc1.x = fmaf(w1, __half2float(__short_as_half(hv1.x)), acc1.x);
        acc1.y = fmaf(w1, __half2float(__short_as_half(hv1.y)), acc1.y);
        acc1.z = fmaf(w1, __half2float(__short_as_half(hv1.z)), acc1.z);
        acc1.w = fmaf(w1, __half2float(__short_as_half(hv1.w)), acc1.w);
    }
    if (i < s1) {
        int src0 = csr_src[i];
        float e0 = as[src0] + adv;
        short4 hv0 = h4[(size_t)src0 * 16 + l16];
        e0 = (e0 >= 0.0f) ? e0 : NEG_SLOPE * e0;
        float w0 = __expf(e0);
        l0 += w0;
        acc0.x = fmaf(w0, __half2float(__short_as_half(hv0.x)), acc0.x);
        acc0.y = fmaf(w0, __half2float(__short_as_half(hv0.y)), acc0.y);
        acc0.z = fmaf(w0, __half2float(__short_as_half(hv0.z)), acc0.z);
        acc0.w = fmaf(w0, __half2float(__short_as_half(hv0.w)), acc0.w);
    }
    float inv = 1.0f / (l0 + l1 + 1e-16f);
    float4 r;
    r.x = (acc0.x + acc1.x) * inv;
    r.y = (acc0.y + acc1.y) * inv;
    r.z = (acc0.z + acc1.z) * inv;
    r.w = (acc0.w + acc1.w) * inv;
    if (BR) {
        float4 b = ((const float4*)bias)[l16];
        r.x = fmaxf(r.x + b.x, 0.0f);
        r.y = fmaxf(r.y + b.y, 0.0f);
        r.z = fmaxf(r.z + b.z, 0.0f);
        r.w = fmaxf(r.w + b.w, 0.0f);
    }
    ((float4*)out)[(size_t)n * 16 + l16] = r;
}

// block = 256 (4 waves) per graph: wave w strides rows start+w,+4,... so 4
// independent 256B loads are in flight per block (round 15: 1-wave version
// was latency-bound at 16% occupancy, 49.6 us). LDS-combine then wave 0 runs
// the tiny MLP.
__global__ __launch_bounds__(256) void pool_mlp_k(
    const float* __restrict__ hfin, const float* __restrict__ hb,
    const int* __restrict__ batch, int N,
    const float* __restrict__ fc1W, const float* __restrict__ fc1b,
    const float* __restrict__ fc2W, const float* __restrict__ fc2b,
    const float* __restrict__ fc3W, const float* __restrict__ fc3b,
    float* __restrict__ out) {
    __shared__ float psum[4][64];
    __shared__ float pmax[4][64];
    __shared__ float lds[192];
    int g = blockIdx.x;
    int lane = threadIdx.x & 63;
    int w = threadIdx.x >> 6;
    // segment bounds via binary search (all threads redundantly; L2-hot)
    int lo = 0, hi = N;
    while (lo < hi) { int mid = (lo + hi) >> 1; if (batch[mid] < g) lo = mid + 1; else hi = mid; }
    int start = lo;
    lo = start; hi = N;
    while (lo < hi) { int mid = (lo + hi) >> 1; if (batch[mid] < g + 1) lo = mid + 1; else hi = mid; }
    int end = lo;
    float bias = hb[lane];
    float sum = 0.0f, mx = -INFINITY;
    for (int n = start + w; n < end; n += 4) {
        float v = hfin[(size_t)n * HD + lane] + bias;
        sum += v;
        mx = fmaxf(mx, v);
    }
    psum[w][lane] = sum;
    pmax[w][lane] = mx;
    __syncthreads();
    if (w == 0) {
        int cnt = end - start;
        float s = psum[0][lane] + psum[1][lane] + psum[2][lane] + psum[3][lane];
        float m = fmaxf(fmaxf(pmax[0][lane], pmax[1][lane]),
                        fmaxf(pmax[2][lane], pmax[3][lane]));
        lds[lane] = (cnt > 0) ? s / (float)cnt : 0.0f;
        lds[64 + lane] = (cnt > 0) ? m : 0.0f;
    }
    __syncthreads();
    if (w == 0) {
        float o1 = fc1b[lane];
        for (int k = 0; k < 128; k++) o1 += lds[k] * fc1W[k * 64 + lane];
        o1 = fmaxf(o1, 0.0f);
        __builtin_amdgcn_s_barrier();  // wave-0 internal only; others done
        lds[128 + lane] = o1;          // stash o1 (slots 128..191)
        float o2 = 0.0f;
        if (lane < 32) {
            o2 = fc2b[lane];
            for (int k = 0; k < 64; k++) o2 += lds[128 + k] * fc2W[k * 32 + lane];
            o2 = fmaxf(o2, 0.0f);
        }
        // reduce o3 = sum_k relu(o2)[k]*fc3W[k] across lanes 0..31 via shuffle
        float part = (lane < 32) ? o2 * fc3W[lane] : 0.0f;
#pragma unroll
        for (int off = 32; off; off >>= 1) part += __shfl_xor(part, off);
        if (lane == 0) out[g] = part + fc3b[0];
    }
}

static inline size_t align256(size_t x) { return (x + 255) & ~(size_t)255; }

extern "C" void kernel_launch(void* const* d_in, const int* in_sizes, int n_in,
                              void* d_out, int out_size, void* d_ws, size_t ws_size,
                              hipStream_t stream) {
    const float* x      = (const float*)d_in[0];
    const int*   ei     = (const int*)d_in[1];
    const int*   batch  = (const int*)d_in[2];
    const float* embW   = (const float*)d_in[3];
    const float* embB   = (const float*)d_in[4];
    const float* g1W    = (const float*)d_in[5];
    const float* g1as   = (const float*)d_in[6];
    const float* g1ad   = (const float*)d_in[7];
    const float* g1b    = (const float*)d_in[8];
    const float* g2W    = (const float*)d_in[9];
    const float* g2as   = (const float*)d_in[10];
    const float* g2ad   = (const float*)d_in[11];
    const float* g2b    = (const float*)d_in[12];
    const float* fc1W   = (const float*)d_in[13];
    const float* fc1b   = (const float*)d_in[14];
    const float* fc2W   = (const float*)d_in[15];
    const float* fc2b   = (const float*)d_in[16];
    const float* fc3W   = (const float*)d_in[17];
    const float* fc3b   = (const float*)d_in[18];
    float* out = (float*)d_out;

    const int N  = in_sizes[0] / NODE_DIM;   // 200000
    const int E  = in_sizes[1] / 2;          // 1200000
    const int G  = out_size;                 // 2048
    const int NH = N * HD;
    const int NB = (N + (1 << BSH) - 1) >> BSH;  // 391 buckets

    char* ws = (char*)d_ws;
    float*  bufA    = (float*)ws;  ws += align256((size_t)NH * 4);
    __half* bufB    = (__half*)ws; ws += align256((size_t)NH * 2);
    float*  as_buf  = (float*)ws;  ws += align256((size_t)N * 4);
    float*  ad_buf  = (float*)ws;  ws += align256((size_t)N * 4);
    int*    deg     = (int*)ws;    ws += align256((size_t)N * 4);
    int*    off     = (int*)ws;    ws += align256((size_t)(N + 1) * 4);
    int*    cursor  = (int*)ws;    ws += align256((size_t)N * 4);
    int*    blksum  = (int*)ws;    ws += align256((size_t)SCAN_B * 4);
    int*    bcnt    = (int*)ws;    ws += align256((size_t)NBMAX * 4);
    int*    bcur    = (int*)ws;    ws += align256((size_t)NBMAX * 4);
    int2*   bpair   = (int2*)ws;   ws += align256((size_t)E * 8);
    int*    csrsrc  = (int*)ws;    ws += align256((size_t)E * 4);

    const int B = 256;
    dim3 blk(B);
    dim3 gr_gemm((N + GT - 1) / GT);                 // 64-node tiles
    dim3 gr_gath(((N + 3) / 4 * 64 + B - 1) / B);    // wave-per-4-nodes
    dim3 gr_epb((E + B * EPB - 1) / (B * EPB));      // bucket kernels
    dim3 gr_e((E + B - 1) / B);                      // per-edge kernels
    dim3 gr_n((N + B - 1) / B);
    const int nb = (N + SCAN_B - 1) / SCAN_B;

    // ---- CSR build: bucket partition (pass A) then hot-window CSR (pass B)
    zero_k<<<dim3((N + B - 1) / B), blk, 0, stream>>>(deg, N);
    zero_k<<<dim3(2), blk, 0, stream>>>(bcnt, NBMAX);
    bucket_hist_k<<<gr_epb, blk, 0, stream>>>(ei, bcnt, E);
    bucket_scan_k<<<dim3(1), dim3(NBMAX), 0, stream>>>(bcnt, bcur, NB);
    partition_k<<<gr_epb, blk, 0, stream>>>(ei, bcur, bpair, E);
    deg_hist_k<<<gr_e, blk, 0, stream>>>(bpair, deg, E);
    scan1_k<<<dim3(nb), dim3(SCAN_B), 0, stream>>>(deg, off, blksum, N);
    scan2_k<<<dim3(1), dim3(SCAN_B), 0, stream>>>(blksum, nb);
    scan3_k<<<gr_n, blk, 0, stream>>>(off, deg, blksum, cursor, N);
    fill2_k<<<gr_e, blk, 0, stream>>>(bpair, cursor, csrsrc, E);

    // ======== GAT layer 1 (embed fused into the gemm) ========
    gemm_alpha_k<true><<<gr_gemm, blk, 0, stream>>>(x, embW, embB, g1W, g1as, g1ad,
                                                    bufB, as_buf, ad_buf, N);
    gather_k<true><<<gr_gath, blk, 0, stream>>>(off, csrsrc, as_buf, ad_buf, bufB,
                                                g1b, bufA, N);

    // ======== GAT layer 2 ========
    gemm_alpha_k<false><<<gr_gemm, blk, 0, stream>>>(bufA, nullptr, nullptr, g2W,
                                                     g2as, g2ad, bufB, as_buf, ad_buf, N);
    gather_k<false><<<gr_gath, blk, 0, stream>>>(off, csrsrc, as_buf, ad_buf, bufB,
                                                 nullptr, bufA, N);

    // ---- pooling + MLP (g2 bias applied here), 4-wave blocks
    pool_mlp_k<<<dim3(G), dim3(256), 0, stream>>>(bufA, g2b, batch, N,
                                                  fc1W, fc1b, fc2W, fc2b, fc3W, fc3b, out);
}